// Round 8
// baseline (148.435 us; speedup 1.0000x reference)
//
#include <hip/hip_runtime.h>
#include <hip/hip_bf16.h>
#include <stdint.h>

// Fused causal attention head, MI355X (gfx950). Round 8.
// Lever: blocks/CU. attn = R6 cooperative body + split-K=4 (1024 blocks,
// 4/CU). proj = 1024 blocks x 16 rows, 6 K-chunks of 64, W+x LDS-staged
// (30 KB -> 4/CU). The ~45us ws-poison fill is fixed harness overhead.

#define EMBED 384
#define HEAD  64
#define NB    4
#define NT    4096
#define NROWS (NB * NT) // 16384

#define SCALE_Q 0.18033688011112042f // 0.125 * log2(e), folded into Q

typedef short bf16x8 __attribute__((ext_vector_type(8)));
typedef float f32x4  __attribute__((ext_vector_type(4)));

__device__ __forceinline__ unsigned short bfround(float f) {
    union { float f; unsigned u; } v; v.f = f;
    return (unsigned short)((v.u + 0x8000u) >> 16);
}
__device__ __forceinline__ unsigned packbf(float lo, float hi) {
    union { float f; unsigned u; } a, b; a.f = lo; b.f = hi;
    return ((a.u + 0x8000u) >> 16) | ((b.u + 0x8000u) & 0xFFFF0000u);
}

// ---------------------------------------------------------------------------
__global__ __launch_bounds__(256)
void wprep_kernel(const float* __restrict__ Wq,
                  const float* __restrict__ Wk,
                  const float* __restrict__ Wv,
                  unsigned short* __restrict__ Wt)
{
    int idx = blockIdx.x * 256 + threadIdx.x;
    int k = idx / 192;
    int n = idx - k * 192;
    int sel = n >> 6, nc = n & 63;
    const float* wp = (sel == 0) ? Wq : ((sel == 1) ? Wk : Wv);
    Wt[n * EMBED + k] = bfround(wp[(size_t)k * HEAD + nc]);
}

// ---------------------------------------------------------------------------
// proj: 1024 blocks x 16 rows x 192 cols. 6 K-chunks of 64; per chunk the
// W slice (192x64) and x slice (16x64, fp32->bf16) are staged to LDS with
// coalesced loads; frags via ds_read_b128 (pitch 72 = 2-way banks, free).
// Wave w owns col tiles {w, 4+w, 8+w} = Q, K, V.
// ---------------------------------------------------------------------------
__global__ __launch_bounds__(256, 4)
void proj_kernel(const float* __restrict__ x,
                 const unsigned short* __restrict__ Wt,
                 unsigned short* __restrict__ Qo,
                 unsigned short* __restrict__ Ko,
                 unsigned short* __restrict__ Vto)
{
    __shared__ __attribute__((aligned(16))) unsigned short wsm[192][72]; // 27.6KB
    __shared__ __attribute__((aligned(16))) unsigned short xs[16][72];   // 2.3KB
    unsigned short (*vbuf)[20] = (unsigned short (*)[20])&wsm[0][0];     // overlay

    const int t    = threadIdx.x;
    const int w    = t >> 6;
    const int lane = t & 63;
    const int quad = lane >> 4;
    const int l16  = lane & 15;
    const int r0   = blockIdx.x * 16;

    f32x4 acc[3];
#pragma unroll
    for (int i = 0; i < 3; ++i) acc[i] = (f32x4){0.f, 0.f, 0.f, 0.f};

    const int srow = t >> 3, sc = t & 7;   // W staging: 8 thr/row
    const int xrow = t >> 4, xc = t & 15;  // x staging: 16 thr/row

    for (int kc = 0; kc < 6; ++kc) {
        const int k0 = kc * 64;
        // issue global loads first (latency overlaps barrier drain)
        uint4 wr[6];
#pragma unroll
        for (int i = 0; i < 6; ++i)
            wr[i] = *(const uint4*)(Wt + (size_t)(srow + i * 32) * EMBED + k0 + sc * 8);
        const float4 xv = *(const float4*)(x + (size_t)(r0 + xrow) * EMBED + k0 + xc * 4);
        __syncthreads(); // prior chunk's frag reads done
#pragma unroll
        for (int i = 0; i < 6; ++i)
            *(uint4*)&wsm[srow + i * 32][sc * 8] = wr[i];
        {
            uint2 pw; pw.x = packbf(xv.x, xv.y); pw.y = packbf(xv.z, xv.w);
            *(uint2*)&xs[xrow][xc * 4] = pw;
        }
        __syncthreads();
        // 2 k-steps x 3 n-tiles
#pragma unroll
        for (int ks = 0; ks < 2; ++ks) {
            bf16x8 a = *(const bf16x8*)&xs[l16][ks * 32 + quad * 8];
#pragma unroll
            for (int i = 0; i < 3; ++i) {
                int nt = w + i * 4;
                bf16x8 b = *(const bf16x8*)&wsm[nt * 16 + l16][ks * 32 + quad * 8];
                acc[i] = __builtin_amdgcn_mfma_f32_16x16x32_bf16(a, b, acc[i], 0, 0, 0);
            }
        }
    }

    // epilogue: C/D layout col=l16, row=quad*4+r (rows 0..15 of this block)
    const int colw = w * 16 + l16;
#pragma unroll
    for (int r = 0; r < 4; ++r) {
        int row = r0 + quad * 4 + r;
        Qo[(size_t)row * HEAD + colw] = bfround(acc[0][r] * SCALE_Q);
        Ko[(size_t)row * HEAD + colw] = bfround(acc[1][r]);
    }
    __syncthreads(); // wsm reads done; becomes vbuf
#pragma unroll
    for (int r = 0; r < 4; ++r)
        vbuf[colw][quad * 4 + r] = bfround(acc[2][r]); // [d][s_local]
    __syncthreads();
    {
        const int batch = r0 >> 12;
        const int s0 = r0 & (NT - 1);
        int d = t >> 2, part = t & 3;
        *(uint2*)(Vto + ((size_t)(batch * HEAD + d)) * NT + s0 + part * 4) =
            *(const uint2*)&vbuf[d][part * 4];
    }
}

// ---------------------------------------------------------------------------
// attn: 1024 blocks x 256 thr. u: sp=u>>8 (split 0..3), v=u&255, batch=v&3,
// mi=v>>2, m = (sp&1) ? mi : 63-mi (balances per-CU work under u+256k
// striping). Block = 64 q-rows (wave w: 16), tiles kt = sp, sp+4, ... <= m;
// diag tile m handled by sp == m&3. K/V staged cooperatively to LDS with
// XOR-chunk swizzle; next tile's regs loaded right after the visibility
// barrier so L2 latency hides under compute. Partials -> opart/lpart.
// ---------------------------------------------------------------------------
__global__ __launch_bounds__(256, 4)
void attn_kernel(const unsigned short* __restrict__ Qi,
                 const unsigned short* __restrict__ Ki,
                 const unsigned short* __restrict__ Vti,
                 float* __restrict__ opart,
                 float* __restrict__ lpart)
{
    __shared__ __attribute__((aligned(16))) unsigned short Kt[64][64];
    __shared__ __attribute__((aligned(16))) unsigned short Vs[64][64];
    __shared__ __attribute__((aligned(16))) unsigned short Ps[4][16][72];

    const int t    = threadIdx.x;
    const int w    = t >> 6;
    const int lane = t & 63;
    const int quad = lane >> 4;
    const int l16  = lane & 15;
    const int sw   = l16 & 7; // frag-read swizzle key

    const int u     = blockIdx.x;
    const int sp    = u >> 8;
    const int v     = u & 255;
    const int batch = v & 3;
    const int mi    = v >> 2;
    const int m     = (sp & 1) ? mi : (63 - mi);
    const int ntiles = (m >= sp) ? (((m - sp) >> 2) + 1) : 0;
    const int q0    = m * 64 + w * 16;

    const unsigned short* Kbg = Ki  + (size_t)batch * NT * HEAD;
    const unsigned short* Vbg = Vti + (size_t)batch * HEAD * NT;

    // Q B-frags (one-time; Q carries 0.125*log2e)
    bf16x8 bq0, bq1;
    {
        const unsigned short* qp = Qi + (size_t)(batch * NT + q0 + l16) * HEAD + quad * 8;
        bq0 = *(const bf16x8*)(qp);
        bq1 = *(const bf16x8*)(qp + 32);
    }

    f32x4 o[4];
#pragma unroll
    for (int i = 0; i < 4; ++i) o[i] = (f32x4){0.f, 0.f, 0.f, 0.f};
    float rs = 0.f;

    // staging: thread t covers rows {t>>3, 32+(t>>3)}, chunk t&7 (swizzled)
    const int srow0 = t >> 3, sc = t & 7;
    const int srow1 = srow0 + 32;
    const int scc0 = sc ^ (srow0 & 7);
    const int scc1 = sc ^ (srow1 & 7);

    uint4 kr0, kr1, vr0, vr1;
    if (ntiles > 0) {
        kr0 = *(const uint4*)(Kbg + (size_t)(sp * 64 + srow0) * HEAD + sc * 8);
        kr1 = *(const uint4*)(Kbg + (size_t)(sp * 64 + srow1) * HEAD + sc * 8);
        vr0 = *(const uint4*)(Vbg + (size_t)srow0 * NT + sp * 64 + sc * 8);
        vr1 = *(const uint4*)(Vbg + (size_t)srow1 * NT + sp * 64 + sc * 8);
    }

    for (int j = 0; j < ntiles; ++j) {
        const int kt = sp + 4 * j;
        __syncthreads(); // previous tile's frag reads complete
        *(uint4*)&Kt[srow0][scc0 * 8] = kr0;
        *(uint4*)&Kt[srow1][scc1 * 8] = kr1;
        *(uint4*)&Vs[srow0][scc0 * 8] = vr0;
        *(uint4*)&Vs[srow1][scc1 * 8] = vr1;
        __syncthreads(); // tile visible
        if (j + 1 < ntiles) { // prefetch next tile (hides under compute)
            const int nt4 = (kt + 4) * 64;
            kr0 = *(const uint4*)(Kbg + (size_t)(nt4 + srow0) * HEAD + sc * 8);
            kr1 = *(const uint4*)(Kbg + (size_t)(nt4 + srow1) * HEAD + sc * 8);
            vr0 = *(const uint4*)(Vbg + (size_t)srow0 * NT + nt4 + sc * 8);
            vr1 = *(const uint4*)(Vbg + (size_t)srow1 * NT + nt4 + sc * 8);
        }

        const bool diag = (kt == m);
#pragma unroll
        for (int ts = 0; ts < 4; ++ts) {
            bf16x8 ak0 = *(const bf16x8*)&Kt[ts * 16 + l16][(quad ^ sw) * 8];
            bf16x8 ak1 = *(const bf16x8*)&Kt[ts * 16 + l16][((4 + quad) ^ sw) * 8];
            f32x4 z = (f32x4){0.f, 0.f, 0.f, 0.f};
            z = __builtin_amdgcn_mfma_f32_16x16x32_bf16(ak0, bq0, z, 0, 0, 0);
            z = __builtin_amdgcn_mfma_f32_16x16x32_bf16(ak1, bq1, z, 0, 0, 0);
            // z[r] = S^T[s = kt*64+ts*16+quad*4+r][q = q0+l16], exp2 domain
            float p[4];
#pragma unroll
            for (int r = 0; r < 4; ++r) {
                float pv = __builtin_amdgcn_exp2f(z[r]);
                if (diag) {
                    int sg = ts * 16 + quad * 4 + r;      // s within tile
                    int qg = (m & 63) * 0 + (q0 - m * 64) + l16; // w*16+l16
                    pv = (sg > qg) ? 0.f : pv;
                }
                p[r] = pv;
            }
            rs += (p[0] + p[1]) + (p[2] + p[3]);
            uint2 pw; pw.x = packbf(p[0], p[1]); pw.y = packbf(p[2], p[3]);
            *(uint2*)&Ps[w][l16][ts * 16 + quad * 4] = pw;
        }
        // P C-layout -> A-frags (same-wave LDS roundtrip)
        bf16x8 ap0 = *(const bf16x8*)&Ps[w][l16][quad * 8];
        bf16x8 ap1 = *(const bf16x8*)&Ps[w][l16][32 + quad * 8];
#pragma unroll
        for (int nd = 0; nd < 4; ++nd) {
            bf16x8 av0 = *(const bf16x8*)&Vs[nd * 16 + l16][(quad ^ sw) * 8];
            bf16x8 av1 = *(const bf16x8*)&Vs[nd * 16 + l16][((4 + quad) ^ sw) * 8];
            o[nd] = __builtin_amdgcn_mfma_f32_16x16x32_bf16(ap0, av0, o[nd], 0, 0, 0);
            o[nd] = __builtin_amdgcn_mfma_f32_16x16x32_bf16(ap1, av1, o[nd], 0, 0, 0);
        }
    }

    // rs reduce over quads -> lane holds sum for q = q0 + l16
    rs += __shfl_xor(rs, 16, 64);
    rs += __shfl_xor(rs, 32, 64);
    if (quad == 0)
        lpart[(size_t)sp * NROWS + batch * NT + q0 + l16] = rs;
    float* ob = opart + (size_t)sp * NROWS * HEAD;
#pragma unroll
    for (int r = 0; r < 4; ++r) {
        size_t off = (size_t)(batch * NT + q0 + quad * 4 + r) * HEAD;
#pragma unroll
        for (int nd = 0; nd < 4; ++nd)
            ob[off + nd * 16 + l16] = o[nd][r];
    }
}

// ---------------------------------------------------------------------------
__global__ __launch_bounds__(256)
void combine_kernel(const float* __restrict__ opart,
                    const float* __restrict__ lpart,
                    float* __restrict__ out)
{
    int gid = blockIdx.x * 256 + threadIdx.x;
    int row = gid >> 4;
    int d4  = (gid & 15) * 4;
    f32x4 a = (f32x4){0.f, 0.f, 0.f, 0.f};
    float l = 0.f;
#pragma unroll
    for (int sp = 0; sp < 4; ++sp) {
        a += *(const f32x4*)(opart + (size_t)sp * NROWS * HEAD + (size_t)row * HEAD + d4);
        l += lpart[(size_t)sp * NROWS + row];
    }
    float inv = 1.0f / l;
    a[0] *= inv; a[1] *= inv; a[2] *= inv; a[3] *= inv;
    *(f32x4*)(out + (size_t)row * HEAD + d4) = a;
}

extern "C" void kernel_launch(void* const* d_in, const int* in_sizes, int n_in,
                              void* d_out, int out_size, void* d_ws, size_t ws_size,
                              hipStream_t stream)
{
    const float* x  = (const float*)d_in[0];
    const float* Wq = (const float*)d_in[1];
    const float* Wk = (const float*)d_in[2];
    const float* Wv = (const float*)d_in[3];
    float* out = (float*)d_out;

    // ws: Q | K | V^T (2MB each bf16) | W^T (144KB) | opart (16MB) | lpart (256KB)
    unsigned short* Qw  = (unsigned short*)d_ws;
    unsigned short* Kw  = Qw + (size_t)NROWS * HEAD;
    unsigned short* Vtw = Kw + (size_t)NROWS * HEAD;
    unsigned short* Wtw = Vtw + (size_t)NROWS * HEAD;
    float* opart = (float*)(Wtw + (size_t)192 * EMBED);
    float* lpart = opart + (size_t)4 * NROWS * HEAD;

    wprep_kernel<<<(192 * EMBED) / 256, 256, 0, stream>>>(Wq, Wk, Wv, Wtw);
    proj_kernel<<<NROWS / 16, 256, 0, stream>>>(x, Wtw, Qw, Kw, Vtw);
    attn_kernel<<<1024, 256, 0, stream>>>(Qw, Kw, Vtw, opart, lpart);
    combine_kernel<<<NROWS * 16 / 256, 256, 0, stream>>>(opart, lpart, out);
}

// Round 9
// 137.106 us; speedup vs baseline: 1.0826x; 1.0826x over previous
//
#include <hip/hip_runtime.h>
#include <hip/hip_bf16.h>
#include <stdint.h>

// Fused causal attention head, MI355X (gfx950). Round 9.
// R8 lessons: (a) proj was HBM-write-amplification-bound (63MB writes from
// partial-sector Vt/QK stores by 16-row blocks) -> back to 64-row x 192-col
// blocks: x read once, all output streams write full 128B sectors.
// (b) attn per-tile cost pinned ~3200cyc by correlated in-block chains ->
// more INDEPENDENT blocks/CU: split-K=8, 2048 blocks, 6 blocks/CU (LDS cap).

#define EMBED 384
#define HEAD  64
#define NB    4
#define NT    4096
#define NROWS (NB * NT) // 16384
#define NSPLIT 8

#define SCALE_Q 0.18033688011112042f // 0.125 * log2(e), folded into Q

typedef short bf16x8 __attribute__((ext_vector_type(8)));
typedef float f32x4  __attribute__((ext_vector_type(4)));

__device__ __forceinline__ unsigned short bfround(float f) {
    union { float f; unsigned u; } v; v.f = f;
    return (unsigned short)((v.u + 0x8000u) >> 16);
}
__device__ __forceinline__ unsigned packbf(float lo, float hi) {
    union { float f; unsigned u; } a, b; a.f = lo; b.f = hi;
    return ((a.u + 0x8000u) >> 16) | ((b.u + 0x8000u) & 0xFFFF0000u);
}

// ---------------------------------------------------------------------------
__global__ __launch_bounds__(256)
void wprep_kernel(const float* __restrict__ Wq,
                  const float* __restrict__ Wk,
                  const float* __restrict__ Wv,
                  unsigned short* __restrict__ Wt)
{
    int idx = blockIdx.x * 256 + threadIdx.x;
    int k = idx / 192;
    int n = idx - k * 192;
    int sel = n >> 6, nc = n & 63;
    const float* wp = (sel == 0) ? Wq : ((sel == 1) ? Wk : Wv);
    Wt[n * EMBED + k] = bfround(wp[(size_t)k * HEAD + nc]);
}

// ---------------------------------------------------------------------------
// proj: 256 blocks x 256 thr; block = 64 rows x 192 cols (x read ONCE).
// 6 k-chunks of 64: W[192][64] + x[64][64] staged to LDS (37 KB, pitch 72).
// Wave w = row-tile w (16 rows), all 12 col-tiles (acc = 48 VGPR).
// Outputs: Q/K rows = full 128B sectors; Vt d-rows = full 128B sectors.
// ---------------------------------------------------------------------------
__global__ __launch_bounds__(256, 4)
void proj_kernel(const float* __restrict__ x,
                 const unsigned short* __restrict__ Wt,
                 unsigned short* __restrict__ Qo,
                 unsigned short* __restrict__ Ko,
                 unsigned short* __restrict__ Vto)
{
    __shared__ __attribute__((aligned(16))) unsigned short wsm[192][72]; // 27.6KB
    __shared__ __attribute__((aligned(16))) unsigned short xs[64][72];   //  9.2KB
    unsigned short (*vbuf)[72] = (unsigned short (*)[72])&xs[0][0];      // overlay

    const int t    = threadIdx.x;
    const int w    = t >> 6;
    const int lane = t & 63;
    const int quad = lane >> 4;
    const int l16  = lane & 15;
    const int r0   = blockIdx.x * 64;

    f32x4 acc[12];
#pragma unroll
    for (int i = 0; i < 12; ++i) acc[i] = (f32x4){0.f, 0.f, 0.f, 0.f};

    const int wrow = t >> 3, wc = t & 7;   // W staging: 8 uint4 per 64-k row
    const int xrow = t >> 4, xc = t & 15;  // x staging: 16 float4 per 64-k row

    for (int kc = 0; kc < 6; ++kc) {
        const int k0 = kc * 64;
        // issue global loads first (latency overlaps barrier drain)
        uint4 wr[6];
#pragma unroll
        for (int i = 0; i < 6; ++i)
            wr[i] = *(const uint4*)(Wt + (size_t)(wrow + i * 32) * EMBED + k0 + wc * 8);
        float4 xr[4];
#pragma unroll
        for (int i = 0; i < 4; ++i)
            xr[i] = *(const float4*)(x + (size_t)(r0 + xrow + i * 16) * EMBED + k0 + xc * 4);
        __syncthreads(); // prior chunk's frag reads done
#pragma unroll
        for (int i = 0; i < 6; ++i)
            *(uint4*)&wsm[wrow + i * 32][wc * 8] = wr[i];
#pragma unroll
        for (int i = 0; i < 4; ++i) {
            uint2 pw; pw.x = packbf(xr[i].x, xr[i].y); pw.y = packbf(xr[i].z, xr[i].w);
            *(uint2*)&xs[xrow + i * 16][xc * 4] = pw;
        }
        __syncthreads();
#pragma unroll
        for (int ks = 0; ks < 2; ++ks) {
            bf16x8 a = *(const bf16x8*)&xs[w * 16 + l16][ks * 32 + quad * 8];
#pragma unroll
            for (int nt = 0; nt < 12; ++nt) {
                bf16x8 b = *(const bf16x8*)&wsm[nt * 16 + l16][ks * 32 + quad * 8];
                acc[nt] = __builtin_amdgcn_mfma_f32_16x16x32_bf16(a, b, acc[nt], 0, 0, 0);
            }
        }
    }

    // epilogue: C/D layout col=l16, row=quad*4+r. Q nt0-3, K nt4-7, V nt8-11.
#pragma unroll
    for (int nt = 0; nt < 8; ++nt) {
        int col = (nt & 3) * 16 + l16;
#pragma unroll
        for (int r = 0; r < 4; ++r) {
            int row = r0 + w * 16 + quad * 4 + r;
            if (nt < 4) Qo[(size_t)row * HEAD + col] = bfround(acc[nt][r] * SCALE_Q);
            else        Ko[(size_t)row * HEAD + col] = bfround(acc[nt][r]);
        }
    }
    __syncthreads(); // xs frag reads done; becomes vbuf
#pragma unroll
    for (int nt = 8; nt < 12; ++nt) {
        int d = (nt & 3) * 16 + l16;
#pragma unroll
        for (int r = 0; r < 4; ++r)
            vbuf[d][w * 16 + quad * 4 + r] = bfround(acc[nt][r]);
    }
    __syncthreads();
    {
        const int batch = r0 >> 12;
        const int s0 = r0 & (NT - 1);
#pragma unroll
        for (int i = 0; i < 2; ++i) {
            int idx = t + i * 256;
            int d = idx >> 3, c = idx & 7;
            *(uint4*)(Vto + ((size_t)(batch * HEAD + d)) * NT + s0 + c * 8) =
                *(const uint4*)&vbuf[d][c * 8];
        }
    }
}

// ---------------------------------------------------------------------------
// attn: 2048 blocks x 256 thr, 6 blocks/CU (LDS 25.2KB). u: sp=u>>8 (0..7),
// v=u&255, batch=v&3, mi=v>>2, m = (sp&1)? mi : 63-mi (alternating LPT).
// Block = 64 q-rows (wave w: 16), tiles kt = sp, sp+8, ... <= m; diag tile
// owned by split sp == m&7. K/V cooperatively staged to LDS, XOR-chunk
// swizzle; next tile prefetched into regs after visibility barrier.
// ---------------------------------------------------------------------------
__global__ __launch_bounds__(256, 6)
void attn_kernel(const unsigned short* __restrict__ Qi,
                 const unsigned short* __restrict__ Ki,
                 const unsigned short* __restrict__ Vti,
                 float* __restrict__ opart,
                 float* __restrict__ lpart)
{
    __shared__ __attribute__((aligned(16))) unsigned short Kt[64][64];
    __shared__ __attribute__((aligned(16))) unsigned short Vs[64][64];
    __shared__ __attribute__((aligned(16))) unsigned short Ps[4][16][72];

    const int t    = threadIdx.x;
    const int w    = t >> 6;
    const int lane = t & 63;
    const int quad = lane >> 4;
    const int l16  = lane & 15;
    const int sw   = l16 & 7;

    const int u     = blockIdx.x;
    const int sp    = u >> 8;
    const int v     = u & 255;
    const int batch = v & 3;
    const int mi    = v >> 2;
    const int m     = (sp & 1) ? mi : (63 - mi);
    const int ntiles = (m >= sp) ? (((m - sp) >> 3) + 1) : 0;
    const int q0    = m * 64 + w * 16;

    const unsigned short* Kbg = Ki  + (size_t)batch * NT * HEAD;
    const unsigned short* Vbg = Vti + (size_t)batch * HEAD * NT;

    bf16x8 bq0, bq1;
    {
        const unsigned short* qp = Qi + (size_t)(batch * NT + q0 + l16) * HEAD + quad * 8;
        bq0 = *(const bf16x8*)(qp);
        bq1 = *(const bf16x8*)(qp + 32);
    }

    f32x4 o[4];
#pragma unroll
    for (int i = 0; i < 4; ++i) o[i] = (f32x4){0.f, 0.f, 0.f, 0.f};
    float rs = 0.f;

    const int srow0 = t >> 3, sc = t & 7;
    const int srow1 = srow0 + 32;
    const int scc0 = sc ^ (srow0 & 7);
    const int scc1 = sc ^ (srow1 & 7);

    uint4 kr0, kr1, vr0, vr1;
    if (ntiles > 0) {
        kr0 = *(const uint4*)(Kbg + (size_t)(sp * 64 + srow0) * HEAD + sc * 8);
        kr1 = *(const uint4*)(Kbg + (size_t)(sp * 64 + srow1) * HEAD + sc * 8);
        vr0 = *(const uint4*)(Vbg + (size_t)srow0 * NT + sp * 64 + sc * 8);
        vr1 = *(const uint4*)(Vbg + (size_t)srow1 * NT + sp * 64 + sc * 8);
    }

    for (int j = 0; j < ntiles; ++j) {
        const int kt = sp + 8 * j;
        __syncthreads(); // previous tile's frag reads complete
        *(uint4*)&Kt[srow0][scc0 * 8] = kr0;
        *(uint4*)&Kt[srow1][scc1 * 8] = kr1;
        *(uint4*)&Vs[srow0][scc0 * 8] = vr0;
        *(uint4*)&Vs[srow1][scc1 * 8] = vr1;
        __syncthreads(); // tile visible
        if (j + 1 < ntiles) {
            const int nt4 = (kt + 8) * 64;
            kr0 = *(const uint4*)(Kbg + (size_t)(nt4 + srow0) * HEAD + sc * 8);
            kr1 = *(const uint4*)(Kbg + (size_t)(nt4 + srow1) * HEAD + sc * 8);
            vr0 = *(const uint4*)(Vbg + (size_t)srow0 * NT + nt4 + sc * 8);
            vr1 = *(const uint4*)(Vbg + (size_t)srow1 * NT + nt4 + sc * 8);
        }

        const bool diag = (kt == m);
#pragma unroll
        for (int ts = 0; ts < 4; ++ts) {
            bf16x8 ak0 = *(const bf16x8*)&Kt[ts * 16 + l16][(quad ^ sw) * 8];
            bf16x8 ak1 = *(const bf16x8*)&Kt[ts * 16 + l16][((4 + quad) ^ sw) * 8];
            f32x4 z = (f32x4){0.f, 0.f, 0.f, 0.f};
            z = __builtin_amdgcn_mfma_f32_16x16x32_bf16(ak0, bq0, z, 0, 0, 0);
            z = __builtin_amdgcn_mfma_f32_16x16x32_bf16(ak1, bq1, z, 0, 0, 0);
            // z[r] = S^T[s=tile-local ts*16+quad*4+r][q = q0+l16], exp2 domain
            float p[4];
#pragma unroll
            for (int r = 0; r < 4; ++r) {
                float pv = __builtin_amdgcn_exp2f(z[r]);
                if (diag) {
                    int sg = ts * 16 + quad * 4 + r;
                    int qg = w * 16 + l16;
                    pv = (sg > qg) ? 0.f : pv;
                }
                p[r] = pv;
            }
            rs += (p[0] + p[1]) + (p[2] + p[3]);
            uint2 pw; pw.x = packbf(p[0], p[1]); pw.y = packbf(p[2], p[3]);
            *(uint2*)&Ps[w][l16][ts * 16 + quad * 4] = pw;
        }
        bf16x8 ap0 = *(const bf16x8*)&Ps[w][l16][quad * 8];
        bf16x8 ap1 = *(const bf16x8*)&Ps[w][l16][32 + quad * 8];
#pragma unroll
        for (int nd = 0; nd < 4; ++nd) {
            bf16x8 av0 = *(const bf16x8*)&Vs[nd * 16 + l16][(quad ^ sw) * 8];
            bf16x8 av1 = *(const bf16x8*)&Vs[nd * 16 + l16][((4 + quad) ^ sw) * 8];
            o[nd] = __builtin_amdgcn_mfma_f32_16x16x32_bf16(ap0, av0, o[nd], 0, 0, 0);
            o[nd] = __builtin_amdgcn_mfma_f32_16x16x32_bf16(ap1, av1, o[nd], 0, 0, 0);
        }
    }

    rs += __shfl_xor(rs, 16, 64);
    rs += __shfl_xor(rs, 32, 64);
    if (quad == 0)
        lpart[(size_t)sp * NROWS + batch * NT + q0 + l16] = rs;
    float* ob = opart + (size_t)sp * NROWS * HEAD;
#pragma unroll
    for (int r = 0; r < 4; ++r) {
        size_t off = (size_t)(batch * NT + q0 + quad * 4 + r) * HEAD;
#pragma unroll
        for (int nd = 0; nd < 4; ++nd)
            ob[off + nd * 16 + l16] = o[nd][r];
    }
}

// ---------------------------------------------------------------------------
__global__ __launch_bounds__(256)
void combine_kernel(const float* __restrict__ opart,
                    const float* __restrict__ lpart,
                    float* __restrict__ out)
{
    int gid = blockIdx.x * 256 + threadIdx.x;
    int row = gid >> 4;
    int d4  = (gid & 15) * 4;
    f32x4 a = (f32x4){0.f, 0.f, 0.f, 0.f};
    float l = 0.f;
#pragma unroll
    for (int sp = 0; sp < NSPLIT; ++sp) {
        a += *(const f32x4*)(opart + (size_t)sp * NROWS * HEAD + (size_t)row * HEAD + d4);
        l += lpart[(size_t)sp * NROWS + row];
    }
    float inv = 1.0f / l;
    a[0] *= inv; a[1] *= inv; a[2] *= inv; a[3] *= inv;
    *(f32x4*)(out + (size_t)row * HEAD + d4) = a;
}

extern "C" void kernel_launch(void* const* d_in, const int* in_sizes, int n_in,
                              void* d_out, int out_size, void* d_ws, size_t ws_size,
                              hipStream_t stream)
{
    const float* x  = (const float*)d_in[0];
    const float* Wq = (const float*)d_in[1];
    const float* Wk = (const float*)d_in[2];
    const float* Wv = (const float*)d_in[3];
    float* out = (float*)d_out;

    // ws: Q | K | V^T (2MB each bf16) | W^T (144KB) | opart (32MB) | lpart (512KB)
    unsigned short* Qw  = (unsigned short*)d_ws;
    unsigned short* Kw  = Qw + (size_t)NROWS * HEAD;
    unsigned short* Vtw = Kw + (size_t)NROWS * HEAD;
    unsigned short* Wtw = Vtw + (size_t)NROWS * HEAD;
    float* opart = (float*)(Wtw + (size_t)192 * EMBED);
    float* lpart = opart + (size_t)NSPLIT * NROWS * HEAD;

    wprep_kernel<<<(192 * EMBED) / 256, 256, 0, stream>>>(Wq, Wk, Wv, Wtw);
    proj_kernel<<<NROWS / 64, 256, 0, stream>>>(x, Wtw, Qw, Kw, Vtw);
    attn_kernel<<<NSPLIT * 256, 256, 0, stream>>>(Qw, Kw, Vtw, opart, lpart);
    combine_kernel<<<NROWS * 16 / 256, 256, 0, stream>>>(opart, lpart, out);
}

// Round 10
// 128.957 us; speedup vs baseline: 1.1510x; 1.0632x over previous
//
#include <hip/hip_runtime.h>
#include <hip/hip_bf16.h>
#include <stdint.h>

// Fused causal attention head, MI355X (gfx950). Round 10.
// R9 lesson: strided split-K gives blocks 1..8 tiles; co-resident blocks run
// concurrently so a CU's busy time is the MAX of its blocks, and the drained
// grid leaves no backfill (measured Occ 10% vs 25% expected). Fix: uniform
// chunks of 4 contiguous k-tiles, 2176 blocks (8.5/CU sequential, 6 resident)
// -> continuous backfill. Tile body unchanged (proven). proj/wprep = R9.

#define EMBED 384
#define HEAD  64
#define NB    4
#define NT    4096
#define NROWS (NB * NT) // 16384
#define MAXCH 16        // chunks per q-tile max (m=63 -> 16)

#define SCALE_Q 0.18033688011112042f // 0.125 * log2(e), folded into Q

typedef short bf16x8 __attribute__((ext_vector_type(8)));
typedef float f32x4  __attribute__((ext_vector_type(4)));

__device__ __forceinline__ unsigned short bfround(float f) {
    union { float f; unsigned u; } v; v.f = f;
    return (unsigned short)((v.u + 0x8000u) >> 16);
}
__device__ __forceinline__ unsigned packbf(float lo, float hi) {
    union { float f; unsigned u; } a, b; a.f = lo; b.f = hi;
    return ((a.u + 0x8000u) >> 16) | ((b.u + 0x8000u) & 0xFFFF0000u);
}

// ---------------------------------------------------------------------------
__global__ __launch_bounds__(256)
void wprep_kernel(const float* __restrict__ Wq,
                  const float* __restrict__ Wk,
                  const float* __restrict__ Wv,
                  unsigned short* __restrict__ Wt)
{
    int idx = blockIdx.x * 256 + threadIdx.x;
    int k = idx / 192;
    int n = idx - k * 192;
    int sel = n >> 6, nc = n & 63;
    const float* wp = (sel == 0) ? Wq : ((sel == 1) ? Wk : Wv);
    Wt[n * EMBED + k] = bfround(wp[(size_t)k * HEAD + nc]);
}

// ---------------------------------------------------------------------------
// proj: identical to R9 (256 blocks x 64 rows x 192 cols, full-sector writes).
// ---------------------------------------------------------------------------
__global__ __launch_bounds__(256, 4)
void proj_kernel(const float* __restrict__ x,
                 const unsigned short* __restrict__ Wt,
                 unsigned short* __restrict__ Qo,
                 unsigned short* __restrict__ Ko,
                 unsigned short* __restrict__ Vto)
{
    __shared__ __attribute__((aligned(16))) unsigned short wsm[192][72];
    __shared__ __attribute__((aligned(16))) unsigned short xs[64][72];
    unsigned short (*vbuf)[72] = (unsigned short (*)[72])&xs[0][0];

    const int t    = threadIdx.x;
    const int w    = t >> 6;
    const int lane = t & 63;
    const int quad = lane >> 4;
    const int l16  = lane & 15;
    const int r0   = blockIdx.x * 64;

    f32x4 acc[12];
#pragma unroll
    for (int i = 0; i < 12; ++i) acc[i] = (f32x4){0.f, 0.f, 0.f, 0.f};

    const int wrow = t >> 3, wc = t & 7;
    const int xrow = t >> 4, xc = t & 15;

    for (int kc = 0; kc < 6; ++kc) {
        const int k0 = kc * 64;
        uint4 wr[6];
#pragma unroll
        for (int i = 0; i < 6; ++i)
            wr[i] = *(const uint4*)(Wt + (size_t)(wrow + i * 32) * EMBED + k0 + wc * 8);
        float4 xr[4];
#pragma unroll
        for (int i = 0; i < 4; ++i)
            xr[i] = *(const float4*)(x + (size_t)(r0 + xrow + i * 16) * EMBED + k0 + xc * 4);
        __syncthreads();
#pragma unroll
        for (int i = 0; i < 6; ++i)
            *(uint4*)&wsm[wrow + i * 32][wc * 8] = wr[i];
#pragma unroll
        for (int i = 0; i < 4; ++i) {
            uint2 pw; pw.x = packbf(xr[i].x, xr[i].y); pw.y = packbf(xr[i].z, xr[i].w);
            *(uint2*)&xs[xrow + i * 16][xc * 4] = pw;
        }
        __syncthreads();
#pragma unroll
        for (int ks = 0; ks < 2; ++ks) {
            bf16x8 a = *(const bf16x8*)&xs[w * 16 + l16][ks * 32 + quad * 8];
#pragma unroll
            for (int nt = 0; nt < 12; ++nt) {
                bf16x8 b = *(const bf16x8*)&wsm[nt * 16 + l16][ks * 32 + quad * 8];
                acc[nt] = __builtin_amdgcn_mfma_f32_16x16x32_bf16(a, b, acc[nt], 0, 0, 0);
            }
        }
    }

#pragma unroll
    for (int nt = 0; nt < 8; ++nt) {
        int col = (nt & 3) * 16 + l16;
#pragma unroll
        for (int r = 0; r < 4; ++r) {
            int row = r0 + w * 16 + quad * 4 + r;
            if (nt < 4) Qo[(size_t)row * HEAD + col] = bfround(acc[nt][r] * SCALE_Q);
            else        Ko[(size_t)row * HEAD + col] = bfround(acc[nt][r]);
        }
    }
    __syncthreads();
#pragma unroll
    for (int nt = 8; nt < 12; ++nt) {
        int d = (nt & 3) * 16 + l16;
#pragma unroll
        for (int r = 0; r < 4; ++r)
            vbuf[d][w * 16 + quad * 4 + r] = bfround(acc[nt][r]);
    }
    __syncthreads();
    {
        const int batch = r0 >> 12;
        const int s0 = r0 & (NT - 1);
#pragma unroll
        for (int i = 0; i < 2; ++i) {
            int idx = t + i * 256;
            int d = idx >> 3, c = idx & 7;
            *(uint4*)(Vto + ((size_t)(batch * HEAD + d)) * NT + s0 + c * 8) =
                *(const uint4*)&vbuf[d][c * 8];
        }
    }
}

// ---------------------------------------------------------------------------
// attn: 2176 blocks x 256 thr, 6 blocks/CU. blockIdx: batch = &3, bid = >>2
// (0..543). bid -> (m, c) by descending-m scan: m=63 gets bids 0..15 (16
// chunks), m=62 next 16, ... (nchunks(m) = (m>>2)+1). Chunk c covers
// contiguous k-tiles [4c, min(4c+4, m+1)) -- uniform 4-tile work for 75% of
// blocks, short remainder blocks backfill. Tile body = R9 (proven).
// Partials keyed by chunk c -> opart/lpart planes.
// ---------------------------------------------------------------------------
__global__ __launch_bounds__(256, 6)
void attn_kernel(const unsigned short* __restrict__ Qi,
                 const unsigned short* __restrict__ Ki,
                 const unsigned short* __restrict__ Vti,
                 float* __restrict__ opart,
                 float* __restrict__ lpart)
{
    __shared__ __attribute__((aligned(16))) unsigned short Kt[64][64];
    __shared__ __attribute__((aligned(16))) unsigned short Vs[64][64];
    __shared__ __attribute__((aligned(16))) unsigned short Ps[4][16][72];

    const int t    = threadIdx.x;
    const int w    = t >> 6;
    const int lane = t & 63;
    const int quad = lane >> 4;
    const int l16  = lane & 15;
    const int sw   = l16 & 7;

    const int batch = blockIdx.x & 3;
    int bid = blockIdx.x >> 2; // 0..543, descending-m order (big work first)
    int m = 63;
    int nc = 16;
    while (bid >= nc) { bid -= nc; --m; nc = (m >> 2) + 1; }
    const int c = bid;                       // chunk index within q-tile m
    const int kt0 = c * 4;
    const int ntiles = min(4, m + 1 - kt0);  // 1..4
    const int q0 = m * 64 + w * 16;

    const unsigned short* Kbg = Ki  + (size_t)batch * NT * HEAD;
    const unsigned short* Vbg = Vti + (size_t)batch * HEAD * NT;

    bf16x8 bq0, bq1;
    {
        const unsigned short* qp = Qi + (size_t)(batch * NT + q0 + l16) * HEAD + quad * 8;
        bq0 = *(const bf16x8*)(qp);
        bq1 = *(const bf16x8*)(qp + 32);
    }

    f32x4 o[4];
#pragma unroll
    for (int i = 0; i < 4; ++i) o[i] = (f32x4){0.f, 0.f, 0.f, 0.f};
    float rs = 0.f;

    const int srow0 = t >> 3, sc = t & 7;
    const int srow1 = srow0 + 32;
    const int scc0 = sc ^ (srow0 & 7);
    const int scc1 = sc ^ (srow1 & 7);

    uint4 kr0, kr1, vr0, vr1;
    kr0 = *(const uint4*)(Kbg + (size_t)(kt0 * 64 + srow0) * HEAD + sc * 8);
    kr1 = *(const uint4*)(Kbg + (size_t)(kt0 * 64 + srow1) * HEAD + sc * 8);
    vr0 = *(const uint4*)(Vbg + (size_t)srow0 * NT + kt0 * 64 + sc * 8);
    vr1 = *(const uint4*)(Vbg + (size_t)srow1 * NT + kt0 * 64 + sc * 8);

    for (int j = 0; j < ntiles; ++j) {
        const int kt = kt0 + j;
        __syncthreads(); // previous tile's frag reads complete
        *(uint4*)&Kt[srow0][scc0 * 8] = kr0;
        *(uint4*)&Kt[srow1][scc1 * 8] = kr1;
        *(uint4*)&Vs[srow0][scc0 * 8] = vr0;
        *(uint4*)&Vs[srow1][scc1 * 8] = vr1;
        __syncthreads(); // tile visible
        if (j + 1 < ntiles) { // prefetch next (contiguous -> L2-friendly)
            const int nt4 = (kt + 1) * 64;
            kr0 = *(const uint4*)(Kbg + (size_t)(nt4 + srow0) * HEAD + sc * 8);
            kr1 = *(const uint4*)(Kbg + (size_t)(nt4 + srow1) * HEAD + sc * 8);
            vr0 = *(const uint4*)(Vbg + (size_t)srow0 * NT + nt4 + sc * 8);
            vr1 = *(const uint4*)(Vbg + (size_t)srow1 * NT + nt4 + sc * 8);
        }

        const bool diag = (kt == m);
#pragma unroll
        for (int ts = 0; ts < 4; ++ts) {
            bf16x8 ak0 = *(const bf16x8*)&Kt[ts * 16 + l16][(quad ^ sw) * 8];
            bf16x8 ak1 = *(const bf16x8*)&Kt[ts * 16 + l16][((4 + quad) ^ sw) * 8];
            f32x4 z = (f32x4){0.f, 0.f, 0.f, 0.f};
            z = __builtin_amdgcn_mfma_f32_16x16x32_bf16(ak0, bq0, z, 0, 0, 0);
            z = __builtin_amdgcn_mfma_f32_16x16x32_bf16(ak1, bq1, z, 0, 0, 0);
            // z[r] = S^T[s = ts*16+quad*4+r (tile-local)][q = q0+l16]
            float p[4];
#pragma unroll
            for (int r = 0; r < 4; ++r) {
                float pv = __builtin_amdgcn_exp2f(z[r]);
                if (diag) {
                    int sg = ts * 16 + quad * 4 + r;
                    int qg = w * 16 + l16;
                    pv = (sg > qg) ? 0.f : pv;
                }
                p[r] = pv;
            }
            rs += (p[0] + p[1]) + (p[2] + p[3]);
            uint2 pw; pw.x = packbf(p[0], p[1]); pw.y = packbf(p[2], p[3]);
            *(uint2*)&Ps[w][l16][ts * 16 + quad * 4] = pw;
        }
        bf16x8 ap0 = *(const bf16x8*)&Ps[w][l16][quad * 8];
        bf16x8 ap1 = *(const bf16x8*)&Ps[w][l16][32 + quad * 8];
#pragma unroll
        for (int nd = 0; nd < 4; ++nd) {
            bf16x8 av0 = *(const bf16x8*)&Vs[nd * 16 + l16][(quad ^ sw) * 8];
            bf16x8 av1 = *(const bf16x8*)&Vs[nd * 16 + l16][((4 + quad) ^ sw) * 8];
            o[nd] = __builtin_amdgcn_mfma_f32_16x16x32_bf16(ap0, av0, o[nd], 0, 0, 0);
            o[nd] = __builtin_amdgcn_mfma_f32_16x16x32_bf16(ap1, av1, o[nd], 0, 0, 0);
        }
    }

    rs += __shfl_xor(rs, 16, 64);
    rs += __shfl_xor(rs, 32, 64);
    if (quad == 0)
        lpart[(size_t)c * NROWS + batch * NT + q0 + l16] = rs;
    float* ob = opart + (size_t)c * NROWS * HEAD;
#pragma unroll
    for (int r = 0; r < 4; ++r) {
        size_t off = (size_t)(batch * NT + q0 + quad * 4 + r) * HEAD;
#pragma unroll
        for (int nd = 0; nd < 4; ++nd)
            ob[off + nd * 16 + l16] = o[nd][r];
    }
}

// ---------------------------------------------------------------------------
// combine: per-row chunk count = (m>>2)+1 where m = (row%NT)/64.
// ---------------------------------------------------------------------------
__global__ __launch_bounds__(256)
void combine_kernel(const float* __restrict__ opart,
                    const float* __restrict__ lpart,
                    float* __restrict__ out)
{
    int gid = blockIdx.x * 256 + threadIdx.x;
    int row = gid >> 4;
    int d4  = (gid & 15) * 4;
    int m   = (row & (NT - 1)) >> 6;
    int nch = (m >> 2) + 1;
    f32x4 a = (f32x4){0.f, 0.f, 0.f, 0.f};
    float l = 0.f;
    for (int cc = 0; cc < nch; ++cc) {
        a += *(const f32x4*)(opart + (size_t)cc * NROWS * HEAD + (size_t)row * HEAD + d4);
        l += lpart[(size_t)cc * NROWS + row];
    }
    float inv = 1.0f / l;
    a[0] *= inv; a[1] *= inv; a[2] *= inv; a[3] *= inv;
    *(f32x4*)(out + (size_t)row * HEAD + d4) = a;
}

extern "C" void kernel_launch(void* const* d_in, const int* in_sizes, int n_in,
                              void* d_out, int out_size, void* d_ws, size_t ws_size,
                              hipStream_t stream)
{
    const float* x  = (const float*)d_in[0];
    const float* Wq = (const float*)d_in[1];
    const float* Wk = (const float*)d_in[2];
    const float* Wv = (const float*)d_in[3];
    float* out = (float*)d_out;

    // ws: Q | K | V^T (2MB each bf16) | W^T (144KB) | opart (64MB) | lpart (1MB)
    unsigned short* Qw  = (unsigned short*)d_ws;
    unsigned short* Kw  = Qw + (size_t)NROWS * HEAD;
    unsigned short* Vtw = Kw + (size_t)NROWS * HEAD;
    unsigned short* Wtw = Vtw + (size_t)NROWS * HEAD;
    float* opart = (float*)(Wtw + (size_t)192 * EMBED);
    float* lpart = opart + (size_t)MAXCH * NROWS * HEAD;

    wprep_kernel<<<(192 * EMBED) / 256, 256, 0, stream>>>(Wq, Wk, Wv, Wtw);
    proj_kernel<<<NROWS / 64, 256, 0, stream>>>(x, Wtw, Qw, Kw, Vtw);
    attn_kernel<<<4 * 544, 256, 0, stream>>>(Qw, Kw, Vtw, opart, lpart);
    combine_kernel<<<NROWS * 16 / 256, 256, 0, stream>>>(opart, lpart, out);
}